// Round 6
// baseline (334.871 us; speedup 1.0000x reference)
//
#include <hip/hip_runtime.h>

#define NB 16
#define NL 4096
#define NH 16
#define ND 64
#define NS 4096
#define NM 256

typedef __fp16 f16;
typedef __attribute__((ext_vector_type(8)))  __fp16 f16x8;
typedef __attribute__((ext_vector_type(4)))  __fp16 f16x4;
typedef __attribute__((ext_vector_type(2)))  __fp16 f16x2;
typedef __attribute__((ext_vector_type(4)))  float  f32x4;
typedef __attribute__((ext_vector_type(16))) float  f32x16;

__device__ __forceinline__ void gload_lds16(const void* g, void* l) {
  __builtin_amdgcn_global_load_lds(
      (const __attribute__((address_space(1))) void*)g,
      (__attribute__((address_space(3))) void*)l, 16, 0, 0);
}

__device__ __forceinline__ int pk2(float a, float b) {
  f16x2 t = __builtin_amdgcn_cvt_pkrtz(a, b);
  union { f16x2 h; int i; } u; u.h = t; return u.i;
}

// ---------------- kernel 0: W fp32 -> fp16, A-frag-run layout ----------------
// Wk[kb = k/8][m][k&7] f16 : one f16x8 = the 8-k run MFMA A-operand lane needs.
__global__ __launch_bounds__(256) void k_wcvt(const float* __restrict__ W,
                                              f16* __restrict__ Wk) {
  const int o  = blockIdx.x * 256 + threadIdx.x;  // 131072 = 512 kb x 256 m
  const int m  = o & 255;
  const int kb = o >> 8;
  const float* src = W + (long)m * NS + kb * 8;
  f32x4 v0 = *(const f32x4*)(src);
  f32x4 v1 = *(const f32x4*)(src + 4);
  union { f16x8 v; f16x2 h2[4]; } pk;
  pk.h2[0] = __builtin_amdgcn_cvt_pkrtz(v0[0], v0[1]);
  pk.h2[1] = __builtin_amdgcn_cvt_pkrtz(v0[2], v0[3]);
  pk.h2[2] = __builtin_amdgcn_cvt_pkrtz(v1[0], v1[1]);
  pk.h2[3] = __builtin_amdgcn_cvt_pkrtz(v1[2], v1[3]);
  *(f16x8*)(Wk + (long)o * 8) = pk.v;
}

// ---------------- kernel 1: squeeze GEMM ------------------
// block (512 thr, 8 waves) = one (t,b,h): Out[256 m][64 d] = W(256x4096) @ X(4096x64).
// Wave w owns m-rows [32w,32w+32). W A-frags straight from L2 (Wk layout, coalesced).
// X: reg-prefetch -> cvt -> transposed XT (double-buffered, ONE barrier/iter).
// Outputs (unchanged layouts): Ksq[bh][d/8][m][d&7], Vsq[bh][m/8][d][m&7].
__global__ __launch_bounds__(512, 4) void k_squeeze(
    const f16* __restrict__ Wk, const float* __restrict__ keys,
    const float* __restrict__ values, const float* __restrict__ bias,
    f16* __restrict__ Ksq, f16* __restrict__ Vsq) {
  const int h = blockIdx.x & 15;
  const int b = (blockIdx.x >> 4) & 15;
  const int t = blockIdx.x >> 8;
  const float* __restrict__ X = t ? values : keys;

  __shared__ __align__(16) f16 XT0[64 * 72];  // [n][72] padded, 9 KB
  __shared__ __align__(16) f16 XT1[64 * 72];

  const int tid  = threadIdx.x;
  const int lane = tid & 63;
  const int w    = tid >> 6;     // wave 0..7
  const int l31  = lane & 31;
  const int g    = lane >> 5;    // 0/1

  const int sp = tid & 31;       // s-pair index (rows 2sp, 2sp+1)
  const int ng = tid >> 5;       // n-group 0..15 (cols 4ng..4ng+3)
  const float* Xb = X + ((long)b * NS) * (NH * ND) + h * ND;

  f32x16 acc[2];
#pragma unroll
  for (int di = 0; di < 2; ++di)
#pragma unroll
    for (int r = 0; r < 16; ++r) acc[di][r] = 0.f;

  // prologue: X regs for kt=0
  f32x4 xr[2];
#pragma unroll
  for (int r = 0; r < 2; ++r)
    xr[r] = *(const f32x4*)(Xb + (long)(2 * sp + r) * (NH * ND) + ng * 4);

  for (int kt = 0; kt < 64; ++kt) {
    f16* xt = (kt & 1) ? XT1 : XT0;
    // cvt + transposed write (conflict-free: sp spreads banks)
#pragma unroll
    for (int cc = 0; cc < 4; ++cc)
      *(int*)((char*)xt + (ng * 4 + cc) * 144 + sp * 4) = pk2(xr[0][cc], xr[1][cc]);
    __syncthreads();
    // issue next X loads early (full iter of latency cover)
    if (kt < 63) {
#pragma unroll
      for (int r = 0; r < 2; ++r)
        xr[r] = *(const f32x4*)(Xb + (long)((kt + 1) * 64 + 2 * sp + r) * (NH * ND) + ng * 4);
    }
    // compute: W frags from L2, X frags from LDS
#pragma unroll
    for (int ks = 0; ks < 4; ++ks) {
      const int kb = kt * 8 + ks * 2 + g;
      f16x8 af  = *(const f16x8*)(Wk + ((long)kb * 256 + w * 32 + l31) * 8);
      f16x8 bf0 = *(const f16x8*)((const char*)xt + l31 * 144 + ks * 32 + g * 16);
      f16x8 bf1 = *(const f16x8*)((const char*)xt + (32 + l31) * 144 + ks * 32 + g * 16);
      acc[0] = __builtin_amdgcn_mfma_f32_32x32x16_f16(af, bf0, acc[0], 0, 0, 0);
      acc[1] = __builtin_amdgcn_mfma_f32_32x32x16_f16(af, bf1, acc[1], 0, 0, 0);
    }
  }

  // epilogue: + bias[m], write f16 (same layouts as before)
  const long bh = b * 16 + h;
  if (t == 0) {
    f16* K = Ksq + bh * (NM * ND);  // [d/8][m][d&7]
#pragma unroll
    for (int di = 0; di < 2; ++di)
#pragma unroll
      for (int r = 0; r < 16; ++r) {
        const int m = w * 32 + (r & 3) + 8 * (r >> 2) + 4 * g;
        const int d = di * 32 + l31;
        K[((d >> 3) * 256 + m) * 8 + (d & 7)] = (f16)(acc[di][r] + bias[m]);
      }
  } else {
    f16* V = Vsq + bh * (ND * NM);  // [m/8][d][m&7]
#pragma unroll
    for (int di = 0; di < 2; ++di)
#pragma unroll
      for (int qq = 0; qq < 4; ++qq) {
        const int m0 = w * 32 + 8 * qq + 4 * g;  // m0&7 == 4g
        const int d  = di * 32 + l31;
        f16x2 p0 = __builtin_amdgcn_cvt_pkrtz(acc[di][qq * 4 + 0] + bias[m0 + 0],
                                              acc[di][qq * 4 + 1] + bias[m0 + 1]);
        f16x2 p1 = __builtin_amdgcn_cvt_pkrtz(acc[di][qq * 4 + 2] + bias[m0 + 2],
                                              acc[di][qq * 4 + 3] + bias[m0 + 3]);
        f16x4 pv; pv[0] = p0[0]; pv[1] = p0[1]; pv[2] = p1[0]; pv[3] = p1[1];
        *(f16x4*)(V + ((m0 >> 3) * 64 + d) * 8 + 4 * g) = pv;
      }
  }
}

// ---------------- kernel 2: attention (persistent K/V-in-LDS) ----------------
// (unchanged from R5)
__global__ __launch_bounds__(256, 2) void k_attn(const float* __restrict__ Q,
                                                 const f16* __restrict__ Ksq,
                                                 const f16* __restrict__ Vsq,
                                                 float* __restrict__ Out) {
  const int xcd   = blockIdx.x & 7;
  const int local = blockIdx.x >> 3;        // 0..63
  const int bh    = xcd * 32 + (local >> 1);
  const int chunk = local & 1;
  const int b = bh >> 4, h = bh & 15;

  __shared__ __align__(16) f16 Klds[8 * 256 * 8];   // [u=d/8][m][8]  32 KB
  __shared__ __align__(16) f16 Vlds[32 * 64 * 8];   // [u=m/8][d][8]  32 KB

  const int tid = threadIdx.x, lane = tid & 63, w = tid >> 6;
  const int q = lane & 31, hi = lane >> 5;

  const float* Qlane = Q   + (((long)b * NL + q) * NH + h) * ND;
  float*       Olane = Out + (((long)b * NL + q) * NH + h) * ND;
  const float  c = 0.125f * 1.44269504088896f;

  // issue tile-0 Q loads first (complete while LDS stages)
  f32x4 qv[8];
  {
    const float* qp = Qlane + (long)(chunk * 2048 + w * 32) * (NH * ND) + hi * 8;
#pragma unroll
    for (int kt = 0; kt < 4; ++kt) {
      qv[2 * kt]     = *(const f32x4*)(qp + kt * 16);
      qv[2 * kt + 1] = *(const f32x4*)(qp + kt * 16 + 4);
    }
  }

  // stage K/V (identity copy, global_load_lds 16B)
  {
    const f16* Kg = Ksq + (long)bh * 16384;
    const f16* Vg = Vsq + (long)bh * 16384;
#pragma unroll
    for (int i = 0; i < 8; ++i)
      gload_lds16(Kg + w * 4096 + i * 512 + lane * 8, (char*)Klds + w * 8192 + i * 1024);
#pragma unroll
    for (int i = 0; i < 8; ++i)
      gload_lds16(Vg + w * 4096 + i * 512 + lane * 8, (char*)Vlds + w * 8192 + i * 1024);
  }
  __syncthreads();

  for (int it = 0; it < 16; ++it) {
    const int row0 = chunk * 2048 + it * 128 + w * 32;  // + q per lane

    // convert current Q tile to f16 B-frags
    union { f16x8 v; f16x2 h2[4]; } qb[4];
#pragma unroll
    for (int kt = 0; kt < 4; ++kt) {
      qb[kt].h2[0] = __builtin_amdgcn_cvt_pkrtz(qv[2 * kt][0], qv[2 * kt][1]);
      qb[kt].h2[1] = __builtin_amdgcn_cvt_pkrtz(qv[2 * kt][2], qv[2 * kt][3]);
      qb[kt].h2[2] = __builtin_amdgcn_cvt_pkrtz(qv[2 * kt + 1][0], qv[2 * kt + 1][1]);
      qb[kt].h2[3] = __builtin_amdgcn_cvt_pkrtz(qv[2 * kt + 1][2], qv[2 * kt + 1][3]);
    }

    // prefetch next tile's Q (latency hides under QK+softmax+PV)
    if (it + 1 < 16) {
      const float* qp = Qlane + (long)(row0 + 128) * (NH * ND) + hi * 8;
#pragma unroll
      for (int kt = 0; kt < 4; ++kt) {
        qv[2 * kt]     = *(const f32x4*)(qp + kt * 16);
        qv[2 * kt + 1] = *(const f32x4*)(qp + kt * 16 + 4);
      }
    }

    // QK^T: sa[mf] = S^T[m-frag][qcol]
    f32x16 sa[8];
#pragma unroll
    for (int mf = 0; mf < 8; ++mf)
#pragma unroll
      for (int r = 0; r < 16; ++r) sa[mf][r] = 0.f;

#pragma unroll
    for (int kt = 0; kt < 4; ++kt) {
#pragma unroll
      for (int mf = 0; mf < 8; ++mf) {
        f16x8 ka = *(const f16x8*)((const char*)Klds +
                                   ((2 * kt + hi) * 256 + mf * 32 + q) * 16);
        sa[mf] = __builtin_amdgcn_mfma_f32_32x32x16_f16(ka, qb[kt].v, sa[mf], 0, 0, 0);
      }
    }

    // tree max (== serial max exactly)
    f32x16 mm = sa[0];
#pragma unroll
    for (int mf = 1; mf < 8; ++mf)
#pragma unroll
      for (int r = 0; r < 16; ++r) mm[r] = fmaxf(mm[r], sa[mf][r]);
    float m8_0 = fmaxf(mm[0], mm[8]),  m8_1 = fmaxf(mm[1], mm[9]);
    float m8_2 = fmaxf(mm[2], mm[10]), m8_3 = fmaxf(mm[3], mm[11]);
    float m8_4 = fmaxf(mm[4], mm[12]), m8_5 = fmaxf(mm[5], mm[13]);
    float m8_6 = fmaxf(mm[6], mm[14]), m8_7 = fmaxf(mm[7], mm[15]);
    float mx = fmaxf(fmaxf(fmaxf(m8_0, m8_1), fmaxf(m8_2, m8_3)),
                     fmaxf(fmaxf(m8_4, m8_5), fmaxf(m8_6, m8_7)));
    mx = fmaxf(mx, __shfl_xor(mx, 32));

    // p = exp2((s-mx)*c), tree-sum
#pragma unroll
    for (int mf = 0; mf < 8; ++mf)
#pragma unroll
      for (int r = 0; r < 16; ++r)
        sa[mf][r] = __builtin_amdgcn_exp2f((sa[mf][r] - mx) * c);

    f32x16 t0 = sa[0] + sa[1];
    f32x16 t1 = sa[2] + sa[3];
    f32x16 t2 = sa[4] + sa[5];
    f32x16 t3 = sa[6] + sa[7];
    t0 = (t0 + t1) + (t2 + t3);
    float s8_0 = t0[0] + t0[8],  s8_1 = t0[1] + t0[9];
    float s8_2 = t0[2] + t0[10], s8_3 = t0[3] + t0[11];
    float s8_4 = t0[4] + t0[12], s8_5 = t0[5] + t0[13];
    float s8_6 = t0[6] + t0[14], s8_7 = t0[7] + t0[15];
    float sum = ((s8_0 + s8_1) + (s8_2 + s8_3)) + ((s8_4 + s8_5) + (s8_6 + s8_7));
    sum += __shfl_xor(sum, 32);
    const float inv = 1.0f / sum;

    // PV: normalized P via cvt_pk + permlane32_swap
    f32x16 o[2];
#pragma unroll
    for (int df = 0; df < 2; ++df)
#pragma unroll
      for (int r = 0; r < 16; ++r) o[df][r] = 0.f;

#pragma unroll
    for (int t = 0; t < 16; ++t) {
      const int fp = t >> 1, s = t & 1;
      int a0 = pk2(sa[fp][8 * s + 0] * inv, sa[fp][8 * s + 1] * inv);
      int a1 = pk2(sa[fp][8 * s + 2] * inv, sa[fp][8 * s + 3] * inv);
      int b0 = pk2(sa[fp][8 * s + 4] * inv, sa[fp][8 * s + 5] * inv);
      int b1 = pk2(sa[fp][8 * s + 6] * inv, sa[fp][8 * s + 7] * inv);
      asm volatile("v_permlane32_swap_b32 %0, %1" : "+v"(a0), "+v"(b0));
      asm volatile("v_permlane32_swap_b32 %0, %1" : "+v"(a1), "+v"(b1));
      union { int w4[4]; f16x8 v; } pb;
      pb.w4[0] = a0; pb.w4[1] = a1; pb.w4[2] = b0; pb.w4[3] = b1;
#pragma unroll
      for (int df = 0; df < 2; ++df) {
        f16x8 va = *(const f16x8*)((const char*)Vlds +
                                   ((2 * t + hi) * 64 + df * 32 + q) * 16);
        o[df] = __builtin_amdgcn_mfma_f32_32x32x16_f16(va, pb.v, o[df], 0, 0, 0);
      }
    }

    // store
    float* op = Olane + (long)row0 * (NH * ND);
#pragma unroll
    for (int df = 0; df < 2; ++df)
#pragma unroll
      for (int rq = 0; rq < 4; ++rq) {
        f32x4 st;
        st[0] = o[df][rq * 4 + 0]; st[1] = o[df][rq * 4 + 1];
        st[2] = o[df][rq * 4 + 2]; st[3] = o[df][rq * 4 + 3];
        *(f32x4*)(op + df * 32 + rq * 8 + hi * 4) = st;
      }
  }
}

extern "C" void kernel_launch(void* const* d_in, const int* in_sizes, int n_in,
                              void* d_out, int out_size, void* d_ws, size_t ws_size,
                              hipStream_t stream) {
  const float* Qp   = (const float*)d_in[0];
  const float* Kp   = (const float*)d_in[1];
  const float* Vp   = (const float*)d_in[2];
  const float* Wp   = (const float*)d_in[3];
  const float* bp   = (const float*)d_in[4];
  float*       Outp = (float*)d_out;

  char* ws = (char*)d_ws;
  f16* Wk  = (f16*)ws;                              // 2 MB
  f16* Ksq = (f16*)(ws + (2l << 20));               // 8 MB
  f16* Vsq = (f16*)(ws + (2l << 20) + (8l << 20));  // 8 MB

  hipLaunchKernelGGL(k_wcvt, dim3(512), dim3(256), 0, stream, Wp, Wk);
  hipLaunchKernelGGL(k_squeeze, dim3(512), dim3(512), 0, stream, Wk, Kp, Vp, bp, Ksq, Vsq);
  hipLaunchKernelGGL(k_attn, dim3(512), dim3(256), 0, stream, Qp, Ksq, Vsq, Outp);
}

// Round 7
// 315.324 us; speedup vs baseline: 1.0620x; 1.0620x over previous
//
#include <hip/hip_runtime.h>

#define NB 16
#define NL 4096
#define NH 16
#define ND 64
#define NS 4096
#define NM 256

typedef __fp16 f16;
typedef __attribute__((ext_vector_type(8)))  __fp16 f16x8;
typedef __attribute__((ext_vector_type(4)))  __fp16 f16x4;
typedef __attribute__((ext_vector_type(2)))  __fp16 f16x2;
typedef __attribute__((ext_vector_type(4)))  float  f32x4;
typedef __attribute__((ext_vector_type(16))) float  f32x16;

__device__ __forceinline__ void gload_lds16(const void* g, void* l) {
  __builtin_amdgcn_global_load_lds(
      (const __attribute__((address_space(1))) void*)g,
      (__attribute__((address_space(3))) void*)l, 16, 0, 0);
}

__device__ __forceinline__ int pk2(float a, float b) {
  f16x2 t = __builtin_amdgcn_cvt_pkrtz(a, b);
  union { f16x2 h; int i; } u; u.h = t; return u.i;
}

// ---------------- kernel 0: W fp32 -> fp16, A-frag-run layout ----------------
// Wk[kb = k/8][m][k&7] f16 : one f16x8 = the 8-k run MFMA A-operand lane needs.
__global__ __launch_bounds__(256) void k_wcvt(const float* __restrict__ W,
                                              f16* __restrict__ Wk) {
  const int o  = blockIdx.x * 256 + threadIdx.x;  // 131072 = 512 kb x 256 m
  const int m  = o & 255;
  const int kb = o >> 8;
  const float* src = W + (long)m * NS + kb * 8;
  f32x4 v0 = *(const f32x4*)(src);
  f32x4 v1 = *(const f32x4*)(src + 4);
  union { f16x8 v; f16x2 h2[4]; } pk;
  pk.h2[0] = __builtin_amdgcn_cvt_pkrtz(v0[0], v0[1]);
  pk.h2[1] = __builtin_amdgcn_cvt_pkrtz(v0[2], v0[3]);
  pk.h2[2] = __builtin_amdgcn_cvt_pkrtz(v1[0], v1[1]);
  pk.h2[3] = __builtin_amdgcn_cvt_pkrtz(v1[2], v1[3]);
  *(f16x8*)(Wk + (long)o * 8) = pk.v;
}

// ---------------- kernel 1: squeeze GEMM ------------------
// block (512 thr, 8 waves) = one (t,b,h). Depth-2 X pipeline (xrA/xrB named,
// unroll-2), af L2 loads issued pre-barrier, ONE barrier per 64-k tile.
__global__ __launch_bounds__(512, 4) void k_squeeze(
    const f16* __restrict__ Wk, const float* __restrict__ keys,
    const float* __restrict__ values, const float* __restrict__ bias,
    f16* __restrict__ Ksq, f16* __restrict__ Vsq) {
  const int h = blockIdx.x & 15;
  const int b = (blockIdx.x >> 4) & 15;
  const int t = blockIdx.x >> 8;
  const float* __restrict__ X = t ? values : keys;

  __shared__ __align__(16) f16 XT0[64 * 72];  // [n][72] padded, 9 KB
  __shared__ __align__(16) f16 XT1[64 * 72];

  const int tid  = threadIdx.x;
  const int lane = tid & 63;
  const int w    = tid >> 6;     // wave 0..7
  const int l31  = lane & 31;
  const int g    = lane >> 5;    // 0/1

  const int sp = tid & 31;       // s-pair index (rows 2sp, 2sp+1)
  const int ng = tid >> 5;       // n-group 0..15 (cols 4ng..4ng+3)
  const float* Xb = X + ((long)b * NS) * (NH * ND) + h * ND;

  f32x16 acc[2];
#pragma unroll
  for (int di = 0; di < 2; ++di)
#pragma unroll
    for (int r = 0; r < 16; ++r) acc[di][r] = 0.f;

  // prologue: X regs for kt=0 (A) and kt=1 (B) — 2 tiles in flight
  f32x4 xrA[2], xrB[2];
#pragma unroll
  for (int r = 0; r < 2; ++r)
    xrA[r] = *(const f32x4*)(Xb + (long)(2 * sp + r) * (NH * ND) + ng * 4);
#pragma unroll
  for (int r = 0; r < 2; ++r)
    xrB[r] = *(const f32x4*)(Xb + (long)(64 + 2 * sp + r) * (NH * ND) + ng * 4);

  const f16* Wlane = Wk + ((long)g * 256 + w * 32 + l31) * 8;

  for (int kt2 = 0; kt2 < 32; ++kt2) {
    // ================= even sub-iter: kt = 2*kt2, buffer XT0, regs xrA ======
    {
      const int kt = 2 * kt2;
      // issue W A-frag loads (L2-hot) — cover = cvt+write+barrier
      f16x8 af[4];
#pragma unroll
      for (int ks = 0; ks < 4; ++ks)
        af[ks] = *(const f16x8*)(Wlane + ((long)(kt * 8 + ks * 2) * 256) * 8);
      // cvt current tile (frees xrA)
      int p0 = pk2(xrA[0][0], xrA[1][0]);
      int p1 = pk2(xrA[0][1], xrA[1][1]);
      int p2 = pk2(xrA[0][2], xrA[1][2]);
      int p3 = pk2(xrA[0][3], xrA[1][3]);
      // issue X loads for kt+2 (2 iterations of latency cover)
      if (kt2 < 31) {
#pragma unroll
        for (int r = 0; r < 2; ++r)
          xrA[r] = *(const f32x4*)(Xb + (long)((kt + 2) * 64 + 2 * sp + r) * (NH * ND) + ng * 4);
      }
      *(int*)((char*)XT0 + (ng * 4 + 0) * 144 + sp * 4) = p0;
      *(int*)((char*)XT0 + (ng * 4 + 1) * 144 + sp * 4) = p1;
      *(int*)((char*)XT0 + (ng * 4 + 2) * 144 + sp * 4) = p2;
      *(int*)((char*)XT0 + (ng * 4 + 3) * 144 + sp * 4) = p3;
      __syncthreads();
#pragma unroll
      for (int ks = 0; ks < 4; ++ks) {
        f16x8 bf0 = *(const f16x8*)((const char*)XT0 + l31 * 144 + ks * 32 + g * 16);
        f16x8 bf1 = *(const f16x8*)((const char*)XT0 + (32 + l31) * 144 + ks * 32 + g * 16);
        acc[0] = __builtin_amdgcn_mfma_f32_32x32x16_f16(af[ks], bf0, acc[0], 0, 0, 0);
        acc[1] = __builtin_amdgcn_mfma_f32_32x32x16_f16(af[ks], bf1, acc[1], 0, 0, 0);
      }
    }
    // ================= odd sub-iter: kt = 2*kt2+1, buffer XT1, regs xrB =====
    {
      const int kt = 2 * kt2 + 1;
      f16x8 af[4];
#pragma unroll
      for (int ks = 0; ks < 4; ++ks)
        af[ks] = *(const f16x8*)(Wlane + ((long)(kt * 8 + ks * 2) * 256) * 8);
      int p0 = pk2(xrB[0][0], xrB[1][0]);
      int p1 = pk2(xrB[0][1], xrB[1][1]);
      int p2 = pk2(xrB[0][2], xrB[1][2]);
      int p3 = pk2(xrB[0][3], xrB[1][3]);
      if (kt2 < 31) {
#pragma unroll
        for (int r = 0; r < 2; ++r)
          xrB[r] = *(const f32x4*)(Xb + (long)((kt + 2) * 64 + 2 * sp + r) * (NH * ND) + ng * 4);
      }
      *(int*)((char*)XT1 + (ng * 4 + 0) * 144 + sp * 4) = p0;
      *(int*)((char*)XT1 + (ng * 4 + 1) * 144 + sp * 4) = p1;
      *(int*)((char*)XT1 + (ng * 4 + 2) * 144 + sp * 4) = p2;
      *(int*)((char*)XT1 + (ng * 4 + 3) * 144 + sp * 4) = p3;
      __syncthreads();
#pragma unroll
      for (int ks = 0; ks < 4; ++ks) {
        f16x8 bf0 = *(const f16x8*)((const char*)XT1 + l31 * 144 + ks * 32 + g * 16);
        f16x8 bf1 = *(const f16x8*)((const char*)XT1 + (32 + l31) * 144 + ks * 32 + g * 16);
        acc[0] = __builtin_amdgcn_mfma_f32_32x32x16_f16(af[ks], bf0, acc[0], 0, 0, 0);
        acc[1] = __builtin_amdgcn_mfma_f32_32x32x16_f16(af[ks], bf1, acc[1], 0, 0, 0);
      }
    }
  }

  // epilogue: + bias[m], write f16 (layouts unchanged)
  const long bh = b * 16 + h;
  if (t == 0) {
    f16* K = Ksq + bh * (NM * ND);  // [d/8][m][d&7]
#pragma unroll
    for (int di = 0; di < 2; ++di)
#pragma unroll
      for (int r = 0; r < 16; ++r) {
        const int m = w * 32 + (r & 3) + 8 * (r >> 2) + 4 * g;
        const int d = di * 32 + l31;
        K[((d >> 3) * 256 + m) * 8 + (d & 7)] = (f16)(acc[di][r] + bias[m]);
      }
  } else {
    f16* V = Vsq + bh * (ND * NM);  // [m/8][d][m&7]
#pragma unroll
    for (int di = 0; di < 2; ++di)
#pragma unroll
      for (int qq = 0; qq < 4; ++qq) {
        const int m0 = w * 32 + 8 * qq + 4 * g;  // m0&7 == 4g
        const int d  = di * 32 + l31;
        f16x2 p0 = __builtin_amdgcn_cvt_pkrtz(acc[di][qq * 4 + 0] + bias[m0 + 0],
                                              acc[di][qq * 4 + 1] + bias[m0 + 1]);
        f16x2 p1 = __builtin_amdgcn_cvt_pkrtz(acc[di][qq * 4 + 2] + bias[m0 + 2],
                                              acc[di][qq * 4 + 3] + bias[m0 + 3]);
        f16x4 pv; pv[0] = p0[0]; pv[1] = p0[1]; pv[2] = p1[0]; pv[3] = p1[1];
        *(f16x4*)(V + ((m0 >> 3) * 64 + d) * 8 + 4 * g) = pv;
      }
  }
}

// ---------------- kernel 2: attention (persistent K/V-in-LDS) ----------------
// (unchanged from R5/R6)
__global__ __launch_bounds__(256, 2) void k_attn(const float* __restrict__ Q,
                                                 const f16* __restrict__ Ksq,
                                                 const f16* __restrict__ Vsq,
                                                 float* __restrict__ Out) {
  const int xcd   = blockIdx.x & 7;
  const int local = blockIdx.x >> 3;        // 0..63
  const int bh    = xcd * 32 + (local >> 1);
  const int chunk = local & 1;
  const int b = bh >> 4, h = bh & 15;

  __shared__ __align__(16) f16 Klds[8 * 256 * 8];   // [u=d/8][m][8]  32 KB
  __shared__ __align__(16) f16 Vlds[32 * 64 * 8];   // [u=m/8][d][8]  32 KB

  const int tid = threadIdx.x, lane = tid & 63, w = tid >> 6;
  const int q = lane & 31, hi = lane >> 5;

  const float* Qlane = Q   + (((long)b * NL + q) * NH + h) * ND;
  float*       Olane = Out + (((long)b * NL + q) * NH + h) * ND;
  const float  c = 0.125f * 1.44269504088896f;

  // issue tile-0 Q loads first (complete while LDS stages)
  f32x4 qv[8];
  {
    const float* qp = Qlane + (long)(chunk * 2048 + w * 32) * (NH * ND) + hi * 8;
#pragma unroll
    for (int kt = 0; kt < 4; ++kt) {
      qv[2 * kt]     = *(const f32x4*)(qp + kt * 16);
      qv[2 * kt + 1] = *(const f32x4*)(qp + kt * 16 + 4);
    }
  }

  // stage K/V (identity copy, global_load_lds 16B)
  {
    const f16* Kg = Ksq + (long)bh * 16384;
    const f16* Vg = Vsq + (long)bh * 16384;
#pragma unroll
    for (int i = 0; i < 8; ++i)
      gload_lds16(Kg + w * 4096 + i * 512 + lane * 8, (char*)Klds + w * 8192 + i * 1024);
#pragma unroll
    for (int i = 0; i < 8; ++i)
      gload_lds16(Vg + w * 4096 + i * 512 + lane * 8, (char*)Vlds + w * 8192 + i * 1024);
  }
  __syncthreads();

  for (int it = 0; it < 16; ++it) {
    const int row0 = chunk * 2048 + it * 128 + w * 32;  // + q per lane

    // convert current Q tile to f16 B-frags
    union { f16x8 v; f16x2 h2[4]; } qb[4];
#pragma unroll
    for (int kt = 0; kt < 4; ++kt) {
      qb[kt].h2[0] = __builtin_amdgcn_cvt_pkrtz(qv[2 * kt][0], qv[2 * kt][1]);
      qb[kt].h2[1] = __builtin_amdgcn_cvt_pkrtz(qv[2 * kt][2], qv[2 * kt][3]);
      qb[kt].h2[2] = __builtin_amdgcn_cvt_pkrtz(qv[2 * kt + 1][0], qv[2 * kt + 1][1]);
      qb[kt].h2[3] = __builtin_amdgcn_cvt_pkrtz(qv[2 * kt + 1][2], qv[2 * kt + 1][3]);
    }

    // prefetch next tile's Q (latency hides under QK+softmax+PV)
    if (it + 1 < 16) {
      const float* qp = Qlane + (long)(row0 + 128) * (NH * ND) + hi * 8;
#pragma unroll
      for (int kt = 0; kt < 4; ++kt) {
        qv[2 * kt]     = *(const f32x4*)(qp + kt * 16);
        qv[2 * kt + 1] = *(const f32x4*)(qp + kt * 16 + 4);
      }
    }

    // QK^T: sa[mf] = S^T[m-frag][qcol]
    f32x16 sa[8];
#pragma unroll
    for (int mf = 0; mf < 8; ++mf)
#pragma unroll
      for (int r = 0; r < 16; ++r) sa[mf][r] = 0.f;

#pragma unroll
    for (int kt = 0; kt < 4; ++kt) {
#pragma unroll
      for (int mf = 0; mf < 8; ++mf) {
        f16x8 ka = *(const f16x8*)((const char*)Klds +
                                   ((2 * kt + hi) * 256 + mf * 32 + q) * 16);
        sa[mf] = __builtin_amdgcn_mfma_f32_32x32x16_f16(ka, qb[kt].v, sa[mf], 0, 0, 0);
      }
    }

    // tree max (== serial max exactly)
    f32x16 mm = sa[0];
#pragma unroll
    for (int mf = 1; mf < 8; ++mf)
#pragma unroll
      for (int r = 0; r < 16; ++r) mm[r] = fmaxf(mm[r], sa[mf][r]);
    float m8_0 = fmaxf(mm[0], mm[8]),  m8_1 = fmaxf(mm[1], mm[9]);
    float m8_2 = fmaxf(mm[2], mm[10]), m8_3 = fmaxf(mm[3], mm[11]);
    float m8_4 = fmaxf(mm[4], mm[12]), m8_5 = fmaxf(mm[5], mm[13]);
    float m8_6 = fmaxf(mm[6], mm[14]), m8_7 = fmaxf(mm[7], mm[15]);
    float mx = fmaxf(fmaxf(fmaxf(m8_0, m8_1), fmaxf(m8_2, m8_3)),
                     fmaxf(fmaxf(m8_4, m8_5), fmaxf(m8_6, m8_7)));
    mx = fmaxf(mx, __shfl_xor(mx, 32));

    // p = exp2((s-mx)*c), tree-sum
#pragma unroll
    for (int mf = 0; mf < 8; ++mf)
#pragma unroll
      for (int r = 0; r < 16; ++r)
        sa[mf][r] = __builtin_amdgcn_exp2f((sa[mf][r] - mx) * c);

    f32x16 t0 = sa[0] + sa[1];
    f32x16 t1 = sa[2] + sa[3];
    f32x16 t2 = sa[4] + sa[5];
    f32x16 t3 = sa[6] + sa[7];
    t0 = (t0 + t1) + (t2 + t3);
    float s8_0 = t0[0] + t0[8],  s8_1 = t0[1] + t0[9];
    float s8_2 = t0[2] + t0[10], s8_3 = t0[3] + t0[11];
    float s8_4 = t0[4] + t0[12], s8_5 = t0[5] + t0[13];
    float s8_6 = t0[6] + t0[14], s8_7 = t0[7] + t0[15];
    float sum = ((s8_0 + s8_1) + (s8_2 + s8_3)) + ((s8_4 + s8_5) + (s8_6 + s8_7));
    sum += __shfl_xor(sum, 32);
    const float inv = 1.0f / sum;

    // PV: normalized P via cvt_pk + permlane32_swap
    f32x16 o[2];
#pragma unroll
    for (int df = 0; df < 2; ++df)
#pragma unroll
      for (int r = 0; r < 16; ++r) o[df][r] = 0.f;

#pragma unroll
    for (int t = 0; t < 16; ++t) {
      const int fp = t >> 1, s = t & 1;
      int a0 = pk2(sa[fp][8 * s + 0] * inv, sa[fp][8 * s + 1] * inv);
      int a1 = pk2(sa[fp][8 * s + 2] * inv, sa[fp][8 * s + 3] * inv);
      int b0 = pk2(sa[fp][8 * s + 4] * inv, sa[fp][8 * s + 5] * inv);
      int b1 = pk2(sa[fp][8 * s + 6] * inv, sa[fp][8 * s + 7] * inv);
      asm volatile("v_permlane32_swap_b32 %0, %1" : "+v"(a0), "+v"(b0));
      asm volatile("v_permlane32_swap_b32 %0, %1" : "+v"(a1), "+v"(b1));
      union { int w4[4]; f16x8 v; } pb;
      pb.w4[0] = a0; pb.w4[1] = a1; pb.w4[2] = b0; pb.w4[3] = b1;
#pragma unroll
      for (int df = 0; df < 2; ++df) {
        f16x8 va = *(const f16x8*)((const char*)Vlds +
                                   ((2 * t + hi) * 64 + df * 32 + q) * 16);
        o[df] = __builtin_amdgcn_mfma_f32_32x32x16_f16(va, pb.v, o[df], 0, 0, 0);
      }
    }

    // store
    float* op = Olane + (long)row0 * (NH * ND);
#pragma unroll
    for (int df = 0; df < 2; ++df)
#pragma unroll
      for (int rq = 0; rq < 4; ++rq) {
        f32x4 st;
        st[0] = o[df][rq * 4 + 0]; st[1] = o[df][rq * 4 + 1];
        st[2] = o[df][rq * 4 + 2]; st[3] = o[df][rq * 4 + 3];
        *(f32x4*)(op + df * 32 + rq * 8 + hi * 4) = st;
      }
  }
}

extern "C" void kernel_launch(void* const* d_in, const int* in_sizes, int n_in,
                              void* d_out, int out_size, void* d_ws, size_t ws_size,
                              hipStream_t stream) {
  const float* Qp   = (const float*)d_in[0];
  const float* Kp   = (const float*)d_in[1];
  const float* Vp   = (const float*)d_in[2];
  const float* Wp   = (const float*)d_in[3];
  const float* bp   = (const float*)d_in[4];
  float*       Outp = (float*)d_out;

  char* ws = (char*)d_ws;
  f16* Wk  = (f16*)ws;                              // 2 MB
  f16* Ksq = (f16*)(ws + (2l << 20));               // 8 MB
  f16* Vsq = (f16*)(ws + (2l << 20) + (8l << 20));  // 8 MB

  hipLaunchKernelGGL(k_wcvt, dim3(512), dim3(256), 0, stream, Wp, Wk);
  hipLaunchKernelGGL(k_squeeze, dim3(512), dim3(512), 0, stream, Wk, Kp, Vp, bp, Ksq, Vsq);
  hipLaunchKernelGGL(k_attn, dim3(512), dim3(256), 0, stream, Qp, Ksq, Vsq, Outp);
}